// Round 5
// baseline (642.009 us; speedup 1.0000x reference)
//
#include <hip/hip_runtime.h>
#include <math.h>

#define D 128
#define NG 1024          // graphs
#define NBLK 512         // blocks per work type (pos / neg / kl)

typedef __bf16 bf16x8 __attribute__((ext_vector_type(8)));
typedef float f32x4 __attribute__((ext_vector_type(4)));

#define MFMA __builtin_amdgcn_mfma_f32_16x16x32_bf16

// lgkm-only barrier: does NOT drain vmcnt, so prefetched global loads stay in
// flight across tile boundaries. sched_barrier(0) fences per rule #18.
__device__ __forceinline__ void bar_lds() {
    __builtin_amdgcn_sched_barrier(0);
    asm volatile("s_waitcnt lgkmcnt(0)" ::: "memory");
    __builtin_amdgcn_s_barrier();
    __builtin_amdgcn_sched_barrier(0);
}

// two f32 -> packed bf16 dword (RNE)
__device__ __forceinline__ unsigned pk2(float a, float b) {
    union { __bf16 h[2]; unsigned u; } x;
    x.h[0] = (__bf16)a; x.h[1] = (__bf16)b;
    return x.u;
}

__device__ __forceinline__ int lbound(const int* __restrict__ a, int L, int v) {
    int lo = 0, hi = L;
    while (lo < hi) { int m = (lo + hi) >> 1; if (a[m] < v) lo = m + 1; else hi = m; }
    return lo;
}

// BCE(sigmoid(z), ta) with torch -100 log clamps ==
//   ta*min(sp(-z),100) + (1-ta)*min(sp(z),100),  sp(z)=max(z,0)+log1p(exp(-|z|)).
// Fast path: log1p(exp(-az)) = __logf(1+__expf(-az)), az>=0 so arg in (1,2]
// (1-2 ulp; z already carries bf16-GEMM rounding ~1e-3 rel, so this is noise).
__device__ __forceinline__ float softplus_neg_abs(float az) {
    return __logf(1.f + __expf(-az));
}

// Wave-level segmented atomic accumulate; all 64 lanes converged.
__device__ __forceinline__ void seg_atomic(float* __restrict__ seg, int g, float v, bool valid) {
    float tv = valid ? v : 0.f;
    float s = tv;
#pragma unroll
    for (int o = 1; o < 64; o <<= 1) s += __shfl_xor(s, o, 64);
    unsigned long long vb = __ballot(valid);
    if (vb == 0ULL) return;
    int g0 = __shfl(g, __ffsll((unsigned long long)vb) - 1, 64);
    unsigned long long ub = __ballot((!valid) || (g == g0));
    const int lane = (int)(threadIdx.x & 63u);
    if (ub == ~0ULL) {
        if (lane == 0) atomicAdd(seg + g0, s);
    } else {
        if (valid) atomicAdd(seg + g, tv);
    }
}

__device__ __forceinline__ void wave_add(float* __restrict__ dst, float v) {
    float s = v;
#pragma unroll
    for (int o = 1; o < 64; o <<= 1) s += __shfl_xor(s, o, 64);
    if ((threadIdx.x & 63u) == 0) atomicAdd(dst, s);
}

// ---------------------------------------------------------------------------
// shared layout (floats): As 0..4096 | Hbf 4096..8448 (8704 shorts, stride 136)
// P 8448..8960 (posP 256 / negP 512) | b1s 8960 | be1s 9088 | We2s 9216
// b2s 9344 | be2s 9352   => 9360 floats = 37.4 KB
#define SMEM_F 9360

// A-slot swizzle: logical (blk=mt*4+kt, q, m) -> physical m' = (m&8)|((m^g)&7),
// g = kt + 4*(q>>1). Writer's 8 same-edge lanes (ks=0..7) map g to all 8 values
// (Latin square) -> conflict-free write phases. Readers use the same XOR.

template<int BF>
__device__ __forceinline__ void pos_body(float* smem, int brank,
    const float* __restrict__ x, const unsigned short* __restrict__ xb,
    const int* __restrict__ ei, const int* __restrict__ ebatch,
    const float* __restrict__ W1, const float* __restrict__ b1,
    const float* __restrict__ W2, const float* __restrict__ b2,
    const float* __restrict__ We1, const float* __restrict__ be1,
    const float* __restrict__ We2, const float* __restrict__ be2,
    const float* __restrict__ attr,
    float* __restrict__ posSum, float* __restrict__ tot1,
    int E, int ntiles)
{
    unsigned short* As16 = (unsigned short*)smem;
    unsigned short* Hb   = (unsigned short*)(smem + 4096);
    float* posP = smem + 8448;
    float* b1s  = smem + 8960;
    float* be1s = smem + 9088;
    float* We2s = smem + 9216;
    float* b2s  = smem + 9344;
    float* be2s = smem + 9352;

    const int t   = (int)threadIdx.x;
    const int wv  = t >> 6;
    const int l   = t & 63;
    const int sub = l & 15;
    const int q   = l >> 4;

    bf16x8 Bh[2][4];   // wv<4: W1 cols; wv>=4: We1-hi cols
    bf16x8 Bl[2][4];   // wv>=4: We1-lo; wv<4: Bl[0][kt] = W2 fragment

    // ---- one-time B staging: 12 passes through the As region
#pragma unroll
    for (int pass = 0; pass < 12; pass++) {
        const int mm = (pass < 4) ? 0 : 1;
        const int p  = (pass < 8) ? 0 : 1;
        const int kt = pass & 3;
        const float* Wsrc = mm ? We1 : W1;
        __syncthreads();
        {
            const int ct = t >> 6, ln = t & 63;
            const int n  = ct * 16 + (ln & 15);
            const int kb = kt * 32 + (ln >> 4) * 8;
            float f[8];
#pragma unroll
            for (int j = 0; j < 8; j++) {
                float v = Wsrc[(kb + j) * D + n];
                f[j] = p ? (v - (float)(__bf16)v) : v;
            }
            uint4 u;
            u.x = pk2(f[0], f[1]); u.y = pk2(f[2], f[3]);
            u.z = pk2(f[4], f[5]); u.w = pk2(f[6], f[7]);
            *(uint4*)(As16 + (ct * 64 + ln) * 8) = u;
        }
        __syncthreads();
        int ct0 = -1;
        if (mm == 0 && wv < 4)  ct0 = 2 * wv;
        if (mm == 1 && wv >= 4) ct0 = 2 * (wv - 4);
        if (ct0 >= 0) {
            bf16x8 f0 = *(const bf16x8*)(As16 + (ct0 * 64 + l) * 8);
            bf16x8 f1 = *(const bf16x8*)(As16 + ((ct0 + 1) * 64 + l) * 8);
            if (p == 0) { Bh[0][kt] = f0; Bh[1][kt] = f1; }
            else        { Bl[0][kt] = f0; Bl[1][kt] = f1; }
        }
    }
    // wv<4: W2 fragments (B-operand of layer-2 GEMM), cols 7..15 zero
    if (wv < 4) {
#pragma unroll
        for (int kt = 0; kt < 4; kt++) {
            const int kb = kt * 32 + q * 8;
            unsigned v[4];
#pragma unroll
            for (int jj = 0; jj < 4; jj++) {
                v[jj] = (sub < 7)
                    ? pk2(W2[(kb + 2 * jj) * 7 + sub], W2[(kb + 2 * jj + 1) * 7 + sub])
                    : 0u;
            }
            union { uint4 u; bf16x8 b; } cv;
            cv.u.x = v[0]; cv.u.y = v[1]; cv.u.z = v[2]; cv.u.w = v[3];
            Bl[0][kt] = cv.b;
        }
    }
    __syncthreads();
    if (t < 128) { b1s[t] = b1[t]; be1s[t] = be1[t]; We2s[t] = We2[t]; }
    if (t < 7) b2s[t] = b2[t];
    if (t == 7) be2s[0] = be2[0];
    __syncthreads();

    // swizzled reader offsets (per kt, lane-constant)
    int roff[4];
#pragma unroll
    for (int kt = 0; kt < 4; kt++) {
        const int g2 = kt + ((q >> 1) << 2);
        roff[kt] = (q * 16 + ((sub & 8) | ((sub ^ g2) & 7))) * 8;
    }
    // swizzled writer slot (lane-constant)
    const int e_  = t >> 3, ks_ = t & 7;
    const int gw  = (ks_ >> 1) | ((ks_ & 1) << 2);
    const int wsl = ((e_ >> 4) * 4 + (ks_ >> 1)) * 64
                  + ((ks_ & 1) * 2) * 16 + ((e_ & 8) | ((e_ ^ gw) & 7));
    unsigned short* wp = As16 + wsl * 8;
    const int k0_ = ks_ * 16;

    float lpAcc = 0.f;
    const int scA = (sub < 7) ? sub : 6;   // clamped attr column

    // ---- software pipeline prologue: ei 2-deep, x rows 1-deep
    int tile = brank;
    float4 rs0, rs1, rs2, rs3, rd0, rd1, rd2, rd3;   // f32 path
    bf16x8 bs0, bs1, bd0, bd1;                       // bf16 path
    int sN, dN;
    {
        const int Ei0 = tile * 64 + e_;
        const int ix  = Ei0 < E ? Ei0 : E - 1;
        const int s0 = ei[ix], d0 = ei[E + ix];
        if (BF) {
            const bf16x8* ps = (const bf16x8*)(xb + (size_t)s0 * D + k0_);
            const bf16x8* pd = (const bf16x8*)(xb + (size_t)d0 * D + k0_);
            bs0 = ps[0]; bs1 = ps[1]; bd0 = pd[0]; bd1 = pd[1];
        } else {
            const float4* ps = (const float4*)(x + (size_t)s0 * D + k0_);
            const float4* pd = (const float4*)(x + (size_t)d0 * D + k0_);
            rs0 = ps[0]; rs1 = ps[1]; rs2 = ps[2]; rs3 = ps[3];
            rd0 = pd[0]; rd1 = pd[1]; rd2 = pd[2]; rd3 = pd[3];
        }
        const int t1  = tile + NBLK;
        int Ei1 = (t1 < ntiles) ? t1 * 64 + e_ : 0;
        Ei1 = Ei1 < E ? Ei1 : E - 1;               // clamp (E may not be /64)
        sN = ei[Ei1]; dN = ei[E + Ei1];
    }

    for (; tile < ntiles; tile += NBLK) {
        const int base = tile * 64;
        const int Ei = base + e_;
        const bool vE = (Ei < E);
        uint4 u0, u1;
        if (vE) {
            if (BF) {
                float p[16];
#pragma unroll
                for (int i = 0; i < 8; i++) {
                    p[i]     = fmaxf((float)bs0[i] * (float)bd0[i], 0.f);
                    p[8 + i] = fmaxf((float)bs1[i] * (float)bd1[i], 0.f);
                }
                u0.x = pk2(p[0], p[1]);   u0.y = pk2(p[2], p[3]);
                u0.z = pk2(p[4], p[5]);   u0.w = pk2(p[6], p[7]);
                u1.x = pk2(p[8], p[9]);   u1.y = pk2(p[10], p[11]);
                u1.z = pk2(p[12], p[13]); u1.w = pk2(p[14], p[15]);
            } else {
                u0.x = pk2(fmaxf(rs0.x * rd0.x, 0.f), fmaxf(rs0.y * rd0.y, 0.f));
                u0.y = pk2(fmaxf(rs0.z * rd0.z, 0.f), fmaxf(rs0.w * rd0.w, 0.f));
                u0.z = pk2(fmaxf(rs1.x * rd1.x, 0.f), fmaxf(rs1.y * rd1.y, 0.f));
                u0.w = pk2(fmaxf(rs1.z * rd1.z, 0.f), fmaxf(rs1.w * rd1.w, 0.f));
                u1.x = pk2(fmaxf(rs2.x * rd2.x, 0.f), fmaxf(rs2.y * rd2.y, 0.f));
                u1.y = pk2(fmaxf(rs2.z * rd2.z, 0.f), fmaxf(rs2.w * rd2.w, 0.f));
                u1.z = pk2(fmaxf(rs3.x * rd3.x, 0.f), fmaxf(rs3.y * rd3.y, 0.f));
                u1.w = pk2(fmaxf(rs3.z * rd3.z, 0.f), fmaxf(rs3.w * rd3.w, 0.f));
            }
        } else { u0.x = u0.y = u0.z = u0.w = 0u; u1 = u0; }
        *(uint4*)wp = u0;
        *(uint4*)(wp + 128) = u1;
        // issue next tile's x loads now (they fly across both barriers + MFMAs)
        const int t1 = tile + NBLK;
        if (t1 < ntiles) {
            if (BF) {
                const bf16x8* ps = (const bf16x8*)(xb + (size_t)sN * D + k0_);
                const bf16x8* pd = (const bf16x8*)(xb + (size_t)dN * D + k0_);
                bs0 = ps[0]; bs1 = ps[1]; bd0 = pd[0]; bd1 = pd[1];
            } else {
                const float4* ps = (const float4*)(x + (size_t)sN * D + k0_);
                const float4* pd = (const float4*)(x + (size_t)dN * D + k0_);
                rs0 = ps[0]; rs1 = ps[1]; rs2 = ps[2]; rs3 = ps[3];
                rd0 = pd[0]; rd1 = pd[1]; rd2 = pd[2]; rd3 = pd[3];
            }
            const int t2 = t1 + NBLK;
            if (t2 < ntiles) {
                int Ei2 = t2 * 64 + e_;
                Ei2 = Ei2 < E ? Ei2 : E - 1;       // clamp
                sN = ei[Ei2]; dN = ei[E + Ei2];
            }
        }
        // ---- hoisted current-tile loss-operand loads (attr / ebatch):
        // issued ~2 barriers + layer1 ahead of use, off the layer-2 critical path.
        float atr[4]; int gW;
        if (wv < 4) {
#pragma unroll
            for (int r = 0; r < 4; r++) {
                int EiE = base + wv * 16 + q * 4 + r;
                EiE = EiE < E ? EiE : E - 1;
                atr[r] = attr[(size_t)EiE * 9 + scA];
            }
            int EiW = base + wv * 16 + q * 4 + (sub & 3);
            EiW = EiW < E ? EiW : E - 1;
            gW = ebatch[EiW];
        } else {
            int EiP = base + (wv - 4) * 16 + sub;
            EiP = EiP < E ? EiP : E - 1;
            gW = ebatch[EiP];
        }
        bar_lds();                      // barrier G (lgkm only)
        // ---- layer 1
#pragma unroll
        for (int mt = 0; mt < 4; mt++) {
            const int ab = mt * 2048;
            bf16x8 a0 = *(const bf16x8*)(As16 + ab +        roff[0]);
            bf16x8 a1 = *(const bf16x8*)(As16 + ab +  512 + roff[1]);
            bf16x8 a2 = *(const bf16x8*)(As16 + ab + 1024 + roff[2]);
            bf16x8 a3 = *(const bf16x8*)(As16 + ab + 1536 + roff[3]);
            if (wv < 4) {
#pragma unroll
                for (int ct = 0; ct < 2; ct++) {
                    f32x4 c = {0.f, 0.f, 0.f, 0.f};
                    c = MFMA(a0, Bh[ct][0], c, 0, 0, 0);
                    c = MFMA(a1, Bh[ct][1], c, 0, 0, 0);
                    c = MFMA(a2, Bh[ct][2], c, 0, 0, 0);
                    c = MFMA(a3, Bh[ct][3], c, 0, 0, 0);
                    const int jloc = wv * 32 + ct * 16 + sub;
                    const float bb = b1s[jloc];
#pragma unroll
                    for (int r = 0; r < 4; r++)
                        *(__bf16*)(Hb + (mt * 16 + q * 4 + r) * 136 + jloc) =
                            (__bf16)fmaxf(c[r] + bb, 0.f);
                }
            } else {
                float zp0 = 0.f, zp1 = 0.f, zp2 = 0.f, zp3 = 0.f;
#pragma unroll
                for (int ct = 0; ct < 2; ct++) {
                    f32x4 c = {0.f, 0.f, 0.f, 0.f};
                    c = MFMA(a0, Bh[ct][0], c, 0, 0, 0);
                    c = MFMA(a1, Bh[ct][1], c, 0, 0, 0);
                    c = MFMA(a2, Bh[ct][2], c, 0, 0, 0);
                    c = MFMA(a3, Bh[ct][3], c, 0, 0, 0);
                    c = MFMA(a0, Bl[ct][0], c, 0, 0, 0);
                    c = MFMA(a1, Bl[ct][1], c, 0, 0, 0);
                    c = MFMA(a2, Bl[ct][2], c, 0, 0, 0);
                    c = MFMA(a3, Bl[ct][3], c, 0, 0, 0);
                    const int jloc = ((wv & 3) << 5) + ct * 16 + sub;
                    const float bb = be1s[jloc], ww = We2s[jloc];
                    zp0 += fmaxf(c[0] + bb, 0.f) * ww;
                    zp1 += fmaxf(c[1] + bb, 0.f) * ww;
                    zp2 += fmaxf(c[2] + bb, 0.f) * ww;
                    zp3 += fmaxf(c[3] + bb, 0.f) * ww;
                }
#pragma unroll
                for (int o = 1; o < 16; o <<= 1) {
                    zp0 += __shfl_xor(zp0, o, 64);
                    zp1 += __shfl_xor(zp1, o, 64);
                    zp2 += __shfl_xor(zp2, o, 64);
                    zp3 += __shfl_xor(zp3, o, 64);
                }
                if (sub < 4) {
                    float vv = (sub == 0) ? zp0 : (sub == 1) ? zp1 : (sub == 2) ? zp2 : zp3;
                    posP[((wv - 4) << 6) + (mt << 4) + (q << 2) + sub] = vv;
                }
            }
        }
        bar_lds();                      // barrier M
        // ---- layer 2, split across all 8 waves
        if (wv < 4) {
            // attr-BCE only (7 cols): single reduction array, no divergent tail
            f32x4 cS = {0.f, 0.f, 0.f, 0.f};
#pragma unroll
            for (int jt = 0; jt < 4; jt++) {
                bf16x8 hf = *(const bf16x8*)(Hb + (wv * 16 + sub) * 136 + jt * 32 + q * 8);
                cS = MFMA(hf, Bl[0][jt], cS, 0, 0, 0);
            }
            float bceP[4];
#pragma unroll
            for (int r = 0; r < 4; r++) {
                const int EiE = base + wv * 16 + q * 4 + r;
                const bool on = (sub < 7) && (EiE < E);
                const float z  = cS[r] + b2s[scA];
                const float ta = atr[r];
                const float az  = fabsf(z);
                const float L   = softplus_neg_abs(az);
                const float spz = fminf(fmaxf(z, 0.f) + L, 100.f);
                const float spn = fminf(fmaxf(-z, 0.f) + L, 100.f);
                bceP[r] = on ? (ta * spn + (1.f - ta) * spz) : 0.f;
            }
#pragma unroll
            for (int o = 1; o < 16; o <<= 1)
#pragma unroll
                for (int r = 0; r < 4; r++)
                    bceP[r] += __shfl_xor(bceP[r], o, 64);
            const float lossSel = (sub == 0) ? bceP[0] : (sub == 1) ? bceP[1]
                                : (sub == 2) ? bceP[2] : bceP[3];
            const int EiW = base + wv * 16 + q * 4 + (sub & 3);
            const bool act = (sub < 4) && (EiW < E);
            seg_atomic(posSum, gW, lossSel, act);
        } else {
            // edge-pos head loss (ta=1 -> min(sp(-z),100)) for 16 edges/wave
            const int e2 = (wv - 4) * 16 + sub;
            const int EiP = base + e2;
            const bool vP = (EiP < E) && (q == 0);
            const float zp = posP[e2] + posP[64 + e2] + posP[128 + e2]
                           + posP[192 + e2] + be2s[0];
            const float az = fabsf(zp);
            const float L  = softplus_neg_abs(az);
            const float lossP = vP ? fminf(fmaxf(-zp, 0.f) + L, 100.f) : 0.f;
            seg_atomic(posSum, gW, lossP, vP);
            lpAcc += lossP;
        }
    }
    if (wv >= 4) wave_add(tot1, lpAcc);
}

template<int BF>
__device__ __forceinline__ void neg_body(float* smem, int brank,
    const float* __restrict__ x, const unsigned short* __restrict__ xb,
    const int* __restrict__ ei, const int* __restrict__ ebatch,
    const float* __restrict__ We1, const float* __restrict__ be1,
    const float* __restrict__ We2, const float* __restrict__ be2,
    float* __restrict__ negSum, float* __restrict__ tot2,
    int E, int ntiles)
{
    unsigned short* As16 = (unsigned short*)smem;
    float* negP = smem + 8448;           // [8][64]
    float* be1s = smem + 9088;
    float* We2s = smem + 9216;
    float* be2s = smem + 9352;

    const int t   = (int)threadIdx.x;
    const int wv  = t >> 6;
    const int l   = t & 63;
    const int sub = l & 15;
    const int q   = l >> 4;

    bf16x8 Bh[4], Bl[4];
#pragma unroll
    for (int pass = 0; pass < 8; pass++) {
        const int p = pass >> 2, kt = pass & 3;
        __syncthreads();
        {
            const int ct = t >> 6, ln = t & 63;
            const int n  = ct * 16 + (ln & 15);
            const int kb = kt * 32 + (ln >> 4) * 8;
            float f[8];
#pragma unroll
            for (int j = 0; j < 8; j++) {
                float v = We1[(kb + j) * D + n];
                f[j] = p ? (v - (float)(__bf16)v) : v;
            }
            uint4 u;
            u.x = pk2(f[0], f[1]); u.y = pk2(f[2], f[3]);
            u.z = pk2(f[4], f[5]); u.w = pk2(f[6], f[7]);
            *(uint4*)(As16 + (ct * 64 + ln) * 8) = u;
        }
        __syncthreads();
        bf16x8 f0 = *(const bf16x8*)(As16 + (wv * 64 + l) * 8);
        if (p == 0) Bh[kt] = f0; else Bl[kt] = f0;
    }
    __syncthreads();
    if (t < 128) { be1s[t] = be1[t]; We2s[t] = We2[t]; }
    if (t == 128) be2s[0] = be2[0];
    __syncthreads();

    int roff[4];
#pragma unroll
    for (int kt = 0; kt < 4; kt++) {
        const int g2 = kt + ((q >> 1) << 2);
        roff[kt] = (q * 16 + ((sub & 8) | ((sub ^ g2) & 7))) * 8;
    }
    const int e_  = t >> 3, ks_ = t & 7;
    const int gw  = (ks_ >> 1) | ((ks_ & 1) << 2);
    const int wsl = ((e_ >> 4) * 4 + (ks_ >> 1)) * 64
                  + ((ks_ & 1) * 2) * 16 + ((e_ & 8) | ((e_ ^ gw) & 7));
    unsigned short* wp = As16 + wsl * 8;
    const int k0_ = ks_ * 16;

    float lnAcc = 0.f;

    int tile = brank;
    float4 rs0, rs1, rs2, rs3, rd0, rd1, rd2, rd3;
    bf16x8 bs0, bs1, bd0, bd1;
    int sN, dN;
    {
        const int Ei0 = tile * 64 + e_;
        const int ix  = Ei0 < E ? Ei0 : E - 1;
        const int s0 = ei[ix], d0 = ei[E + ix];
        if (BF) {
            const bf16x8* ps = (const bf16x8*)(xb + (size_t)s0 * D + k0_);
            const bf16x8* pd = (const bf16x8*)(xb + (size_t)d0 * D + k0_);
            bs0 = ps[0]; bs1 = ps[1]; bd0 = pd[0]; bd1 = pd[1];
        } else {
            const float4* ps = (const float4*)(x + (size_t)s0 * D + k0_);
            const float4* pd = (const float4*)(x + (size_t)d0 * D + k0_);
            rs0 = ps[0]; rs1 = ps[1]; rs2 = ps[2]; rs3 = ps[3];
            rd0 = pd[0]; rd1 = pd[1]; rd2 = pd[2]; rd3 = pd[3];
        }
        const int t1  = tile + NBLK;
        int Ei1 = (t1 < ntiles) ? t1 * 64 + e_ : 0;
        Ei1 = Ei1 < E ? Ei1 : E - 1;               // clamp
        sN = ei[Ei1]; dN = ei[E + Ei1];
    }

    for (; tile < ntiles; tile += NBLK) {
        const int base = tile * 64;
        const int Ei = base + e_;
        const bool vE = (Ei < E);
        uint4 u0, u1;
        if (vE) {
            if (BF) {
                float p[16];
#pragma unroll
                for (int i = 0; i < 8; i++) {
                    p[i]     = fmaxf((float)bs0[i] * (float)bd0[i], 0.f);
                    p[8 + i] = fmaxf((float)bs1[i] * (float)bd1[i], 0.f);
                }
                u0.x = pk2(p[0], p[1]);   u0.y = pk2(p[2], p[3]);
                u0.z = pk2(p[4], p[5]);   u0.w = pk2(p[6], p[7]);
                u1.x = pk2(p[8], p[9]);   u1.y = pk2(p[10], p[11]);
                u1.z = pk2(p[12], p[13]); u1.w = pk2(p[14], p[15]);
            } else {
                u0.x = pk2(fmaxf(rs0.x * rd0.x, 0.f), fmaxf(rs0.y * rd0.y, 0.f));
                u0.y = pk2(fmaxf(rs0.z * rd0.z, 0.f), fmaxf(rs0.w * rd0.w, 0.f));
                u0.z = pk2(fmaxf(rs1.x * rd1.x, 0.f), fmaxf(rs1.y * rd1.y, 0.f));
                u0.w = pk2(fmaxf(rs1.z * rd1.z, 0.f), fmaxf(rs1.w * rd1.w, 0.f));
                u1.x = pk2(fmaxf(rs2.x * rd2.x, 0.f), fmaxf(rs2.y * rd2.y, 0.f));
                u1.y = pk2(fmaxf(rs2.z * rd2.z, 0.f), fmaxf(rs2.w * rd2.w, 0.f));
                u1.z = pk2(fmaxf(rs3.x * rd3.x, 0.f), fmaxf(rs3.y * rd3.y, 0.f));
                u1.w = pk2(fmaxf(rs3.z * rd3.z, 0.f), fmaxf(rs3.w * rd3.w, 0.f));
            }
        } else { u0.x = u0.y = u0.z = u0.w = 0u; u1 = u0; }
        *(uint4*)wp = u0;
        *(uint4*)(wp + 128) = u1;
        const int t1 = tile + NBLK;
        if (t1 < ntiles) {
            if (BF) {
                const bf16x8* ps = (const bf16x8*)(xb + (size_t)sN * D + k0_);
                const bf16x8* pd = (const bf16x8*)(xb + (size_t)dN * D + k0_);
                bs0 = ps[0]; bs1 = ps[1]; bd0 = pd[0]; bd1 = pd[1];
            } else {
                const float4* ps = (const float4*)(x + (size_t)sN * D + k0_);
                const float4* pd = (const float4*)(x + (size_t)dN * D + k0_);
                rs0 = ps[0]; rs1 = ps[1]; rs2 = ps[2]; rs3 = ps[3];
                rd0 = pd[0]; rd1 = pd[1]; rd2 = pd[2]; rd3 = pd[3];
            }
            const int t2 = t1 + NBLK;
            if (t2 < ntiles) {
                int Ei2 = t2 * 64 + e_;
                Ei2 = Ei2 < E ? Ei2 : E - 1;       // clamp
                sN = ei[Ei2]; dN = ei[E + Ei2];
            }
        }
        // hoisted ebatch load for the tail (wv0 only)
        int gN = 0;
        if (wv == 0) {
            int EiL = base + l;
            EiL = EiL < E ? EiL : E - 1;
            gN = ebatch[EiL];
        }
        bar_lds();
        const int j = wv * 16 + sub;
        const float bb = be1s[j], ww = We2s[j];
#pragma unroll
        for (int mt = 0; mt < 4; mt++) {
            const int ab = mt * 2048;
            bf16x8 a0 = *(const bf16x8*)(As16 + ab +        roff[0]);
            bf16x8 a1 = *(const bf16x8*)(As16 + ab +  512 + roff[1]);
            bf16x8 a2 = *(const bf16x8*)(As16 + ab + 1024 + roff[2]);
            bf16x8 a3 = *(const bf16x8*)(As16 + ab + 1536 + roff[3]);
            f32x4 c = {0.f, 0.f, 0.f, 0.f};
            c = MFMA(a0, Bh[0], c, 0, 0, 0);
            c = MFMA(a1, Bh[1], c, 0, 0, 0);
            c = MFMA(a2, Bh[2], c, 0, 0, 0);
            c = MFMA(a3, Bh[3], c, 0, 0, 0);
            c = MFMA(a0, Bl[0], c, 0, 0, 0);
            c = MFMA(a1, Bl[1], c, 0, 0, 0);
            c = MFMA(a2, Bl[2], c, 0, 0, 0);
            c = MFMA(a3, Bl[3], c, 0, 0, 0);
            float zp0 = fmaxf(c[0] + bb, 0.f) * ww;
            float zp1 = fmaxf(c[1] + bb, 0.f) * ww;
            float zp2 = fmaxf(c[2] + bb, 0.f) * ww;
            float zp3 = fmaxf(c[3] + bb, 0.f) * ww;
#pragma unroll
            for (int o = 1; o < 16; o <<= 1) {
                zp0 += __shfl_xor(zp0, o, 64);
                zp1 += __shfl_xor(zp1, o, 64);
                zp2 += __shfl_xor(zp2, o, 64);
                zp3 += __shfl_xor(zp3, o, 64);
            }
            if (sub < 4) {
                float vv = (sub == 0) ? zp0 : (sub == 1) ? zp1 : (sub == 2) ? zp2 : zp3;
                negP[(wv << 6) + (mt << 4) + (q << 2) + sub] = vv;
            }
        }
        bar_lds();
        if (wv == 0) {
            const int EiL = base + l;
            const bool valid = (EiL < E);
            float zp = be2s[0];
#pragma unroll
            for (int i = 0; i < 8; i++) zp += negP[i * 64 + l];
            float lossN = 0.f;
            if (valid) {
                const float az = fabsf(zp);
                const float L  = softplus_neg_abs(az);
                lossN = fminf(fmaxf(zp, 0.f) + L, 100.f);   // min(sp(z),100)
            }
            seg_atomic(negSum, gN, lossN, valid);
            lnAcc += valid ? lossN : 0.f;
        }
    }
    if (wv == 0) wave_add(tot2, lnAcc);
}

__device__ __forceinline__ void kl_body(int brank,
    const float* __restrict__ xm, const float* __restrict__ xs,
    const int* __restrict__ batch,
    float* __restrict__ klSum, int N)
{
    const int t  = (int)threadIdx.x;
    const int wv = t >> 6, l = t & 63;
    const int hf = l >> 5, li = l & 31;      // 2 rows / wave, 32 lanes each
    const int gwv = brank * 8 + wv;
    for (int rb = gwv * 2; rb < N; rb += NBLK * 16) {
        const int row = rb + hf;
        const bool v = (row < N);
        const int rr = v ? row : (N - 1);
        const float4 mm = *(const float4*)(xm + (size_t)rr * D + li * 4);
        const float4 ss = *(const float4*)(xs + (size_t)rr * D + li * 4);
        float a;
        a  = 1.f + 2.f * fmaxf(__logf(ss.x), -1e4f) - mm.x * mm.x - ss.x * ss.x;
        a += 1.f + 2.f * fmaxf(__logf(ss.y), -1e4f) - mm.y * mm.y - ss.y * ss.y;
        a += 1.f + 2.f * fmaxf(__logf(ss.z), -1e4f) - mm.z * mm.z - ss.z * ss.z;
        a += 1.f + 2.f * fmaxf(__logf(ss.w), -1e4f) - mm.w * mm.w - ss.w * ss.w;
#pragma unroll
        for (int o = 1; o < 32; o <<= 1) a += __shfl_xor(a, o, 64);
        if (li == 0 && v) {
            const int g = batch[row];
            atomicAdd(klSum + g, -0.5f * a);
        }
    }
}

__global__ __launch_bounds__(256)
void conv_kernel(const float* __restrict__ x, unsigned short* __restrict__ xb, int n8) {
    const int i0 = (int)(blockIdx.x * 256 + threadIdx.x);
    const int stride = (int)(gridDim.x * 256);
    for (int j = i0; j < n8; j += stride) {
        const float4 a = ((const float4*)x)[(size_t)j * 2];
        const float4 b = ((const float4*)x)[(size_t)j * 2 + 1];
        uint4 u;
        u.x = pk2(a.x, a.y); u.y = pk2(a.z, a.w);
        u.z = pk2(b.x, b.y); u.w = pk2(b.z, b.w);
        ((uint4*)xb)[j] = u;
    }
}

template<int BF>
__global__ __launch_bounds__(512, 4)
void fused_kernel(const float* __restrict__ x, const unsigned short* __restrict__ xb,
                  const float* __restrict__ attr,
                  const float* __restrict__ xm, const float* __restrict__ xs,
                  const float* __restrict__ W1, const float* __restrict__ b1,
                  const float* __restrict__ W2, const float* __restrict__ b2,
                  const float* __restrict__ We1, const float* __restrict__ be1,
                  const float* __restrict__ We2, const float* __restrict__ be2,
                  const int* __restrict__ ei, const int* __restrict__ ein,
                  const int* __restrict__ eib, const int* __restrict__ einb,
                  const int* __restrict__ batch,
                  float* __restrict__ ws, int E, int N, int ntiles)
{
    __shared__ float smem[SMEM_F];
    const int bid   = (int)blockIdx.x;
    const int btype = bid % 3;
    const int brank = bid / 3;
    float* posSum = ws;
    float* negSum = ws + NG;
    float* klSum  = ws + 2 * NG;
    float* tot    = ws + 3 * NG;
    if (btype == 0)
        pos_body<BF>(smem, brank, x, xb, ei, eib, W1, b1, W2, b2, We1, be1, We2, be2,
                     attr, posSum, tot + 1, E, ntiles);
    else if (btype == 1)
        neg_body<BF>(smem, brank, x, xb, ein, einb, We1, be1, We2, be2,
                     negSum, tot + 2, E, ntiles);
    else
        kl_body(brank, xm, xs, batch, klSum, N);
}

__global__ __launch_bounds__(256)
void final_kernel(const int* __restrict__ eib, const int* __restrict__ einb,
                  const int* __restrict__ nbatch,
                  float* __restrict__ ws, int E, int N, int G) {
    const int g = (int)(blockIdx.x * blockDim.x + threadIdx.x);
    float lg = 0.f;
    if (g < G) {
        const int cP = lbound(eib, E, g + 1) - lbound(eib, E, g);
        const int cN = lbound(einb, E, g + 1) - lbound(einb, E, g);
        const int cB = lbound(nbatch, N, g + 1) - lbound(nbatch, N, g);
        const float fp = fmaxf((float)cP, 1.f);
        const float fn = fmaxf((float)cN, 1.f);
        const float fb = fmaxf((float)cB, 1.f);
        lg = ws[g] / fp + ws[NG + g] / fn + ws[2 * NG + g] / (fb * fb);
    }
#pragma unroll
    for (int o = 1; o < 64; o <<= 1) lg += __shfl_xor(lg, o, 64);
    if ((threadIdx.x & 63u) == 0) atomicAdd(ws + 3 * NG, lg);
}

__global__ void out_kernel(const float* __restrict__ ws, float* __restrict__ out,
                           int E, int G) {
    if (threadIdx.x == 0 && blockIdx.x == 0) {
        out[0] = ws[3 * NG] / (float)G;
        out[1] = 0.5f * (ws[3 * NG + 1] / (float)E + ws[3 * NG + 2] / (float)E);
    }
}

extern "C" void kernel_launch(void* const* d_in, const int* in_sizes, int n_in,
                              void* d_out, int out_size, void* d_ws, size_t ws_size,
                              hipStream_t stream) {
    const float* x    = (const float*)d_in[0];
    const float* attr = (const float*)d_in[1];
    const float* xm   = (const float*)d_in[2];
    const float* xsd  = (const float*)d_in[3];
    const float* W1   = (const float*)d_in[4];
    const float* b1   = (const float*)d_in[5];
    const float* W2   = (const float*)d_in[6];
    const float* b2   = (const float*)d_in[7];
    const float* We1  = (const float*)d_in[8];
    const float* be1  = (const float*)d_in[9];
    const float* We2  = (const float*)d_in[10];
    const float* be2  = (const float*)d_in[11];
    const int* ei     = (const int*)d_in[12];
    const int* ein    = (const int*)d_in[13];
    const int* eib    = (const int*)d_in[14];
    const int* einb   = (const int*)d_in[15];
    const int* batch  = (const int*)d_in[16];

    const int N = in_sizes[0] / D;       // 100000
    const int E = in_sizes[14];          // 600000
    const int G = 1024;

    float* ws = (float*)d_ws;
    unsigned short* xb = (unsigned short*)(ws + 3 * NG + 8);   // 16B-aligned
    const size_t need = (size_t)(3 * NG + 8) * sizeof(float)
                      + (size_t)N * D * sizeof(unsigned short);

    hipMemsetAsync(d_ws, 0, (size_t)(3 * NG + 4) * sizeof(float), stream);

    const int ntiles = (E + 63) / 64;
    if (ws_size >= need) {
        conv_kernel<<<2048, 256, 0, stream>>>(x, xb, N * D / 8);
        fused_kernel<1><<<3 * NBLK, 512, 0, stream>>>(x, xb, attr, xm, xsd,
                                                      W1, b1, W2, b2, We1, be1, We2, be2,
                                                      ei, ein, eib, einb, batch,
                                                      ws, E, N, ntiles);
    } else {
        fused_kernel<0><<<3 * NBLK, 512, 0, stream>>>(x, xb, attr, xm, xsd,
                                                      W1, b1, W2, b2, We1, be1, We2, be2,
                                                      ei, ein, eib, einb, batch,
                                                      ws, E, N, ntiles);
    }
    final_kernel<<<(G + 255) / 256, 256, 0, stream>>>(eib, einb, batch,
                                                      ws, E, N, G);
    out_kernel<<<1, 64, 0, stream>>>(ws, (float*)d_out, E, G);
}

// Round 7
// 525.176 us; speedup vs baseline: 1.2225x; 1.2225x over previous
//
#include <hip/hip_runtime.h>
#include <math.h>

#define D 128
#define NG 1024          // graphs
#define NB 512           // total blocks = 2 per CU, single dispatch round

typedef __bf16 bf16x8 __attribute__((ext_vector_type(8)));
typedef float f32x4 __attribute__((ext_vector_type(4)));

#define MFMA __builtin_amdgcn_mfma_f32_16x16x32_bf16

// lgkm-only barrier: does NOT drain vmcnt, so prefetched global loads stay in
// flight across tile boundaries. sched_barrier(0) fences per rule #18.
__device__ __forceinline__ void bar_lds() {
    __builtin_amdgcn_sched_barrier(0);
    asm volatile("s_waitcnt lgkmcnt(0)" ::: "memory");
    __builtin_amdgcn_s_barrier();
    __builtin_amdgcn_sched_barrier(0);
}

// two f32 -> packed bf16 dword (RNE)
__device__ __forceinline__ unsigned pk2(float a, float b) {
    union { __bf16 h[2]; unsigned u; } x;
    x.h[0] = (__bf16)a; x.h[1] = (__bf16)b;
    return x.u;
}

__device__ __forceinline__ int lbound(const int* __restrict__ a, int L, int v) {
    int lo = 0, hi = L;
    while (lo < hi) { int m = (lo + hi) >> 1; if (a[m] < v) lo = m + 1; else hi = m; }
    return lo;
}

// BCE(sigmoid(z), ta) with torch -100 log clamps ==
//   ta*min(sp(-z),100) + (1-ta)*min(sp(z),100),  sp(z)=max(z,0)+log1p(exp(-|z|)).
__device__ __forceinline__ float softplus_neg_abs(float az) {
    return __logf(1.f + __expf(-az));
}

// Wave-level segmented atomic accumulate; all 64 lanes converged.
__device__ __forceinline__ void seg_atomic(float* __restrict__ seg, int g, float v, bool valid) {
    float tv = valid ? v : 0.f;
    float s = tv;
#pragma unroll
    for (int o = 1; o < 64; o <<= 1) s += __shfl_xor(s, o, 64);
    unsigned long long vb = __ballot(valid);
    if (vb == 0ULL) return;
    int g0 = __shfl(g, __ffsll((unsigned long long)vb) - 1, 64);
    unsigned long long ub = __ballot((!valid) || (g == g0));
    const int lane = (int)(threadIdx.x & 63u);
    if (ub == ~0ULL) {
        if (lane == 0) atomicAdd(seg + g0, s);
    } else {
        if (valid) atomicAdd(seg + g, tv);
    }
}

__device__ __forceinline__ void wave_add(float* __restrict__ dst, float v) {
    float s = v;
#pragma unroll
    for (int o = 1; o < 64; o <<= 1) s += __shfl_xor(s, o, 64);
    if ((threadIdx.x & 63u) == 0) atomicAdd(dst, s);
}

// ---------------------------------------------------------------------------
// shared layout (floats): As 0..4096 (8192 shorts) | Hb 4096..8448 (8704 shorts,
// stride 136) | P 8448..8960 ([8][64]) | b2s 8960 | be2s 8968  => 35.9 KB
#define SMEM_F 8976

// A-slot swizzle: logical (blk=mt*4+kt, q, m) -> physical m' = (m&8)|((m^g)&7),
// g = kt + 4*(q>>1). Writer's 8 same-edge lanes (ks=0..7) map g to all 8 values
// (Latin square) -> conflict-free write phases. Readers use the same XOR.

template<int BF>
__device__ __forceinline__ void pack_tile(bool vE,
    const bf16x8& bs0, const bf16x8& bs1, const bf16x8& bd0, const bf16x8& bd1,
    const float4& rs0, const float4& rs1, const float4& rs2, const float4& rs3,
    const float4& rd0, const float4& rd1, const float4& rd2, const float4& rd3,
    uint4& u0, uint4& u1)
{
    if (vE) {
        if (BF) {
            float p[16];
#pragma unroll
            for (int i = 0; i < 8; i++) {
                p[i]     = fmaxf((float)bs0[i] * (float)bd0[i], 0.f);
                p[8 + i] = fmaxf((float)bs1[i] * (float)bd1[i], 0.f);
            }
            u0.x = pk2(p[0], p[1]);   u0.y = pk2(p[2], p[3]);
            u0.z = pk2(p[4], p[5]);   u0.w = pk2(p[6], p[7]);
            u1.x = pk2(p[8], p[9]);   u1.y = pk2(p[10], p[11]);
            u1.z = pk2(p[12], p[13]); u1.w = pk2(p[14], p[15]);
        } else {
            u0.x = pk2(fmaxf(rs0.x * rd0.x, 0.f), fmaxf(rs0.y * rd0.y, 0.f));
            u0.y = pk2(fmaxf(rs0.z * rd0.z, 0.f), fmaxf(rs0.w * rd0.w, 0.f));
            u0.z = pk2(fmaxf(rs1.x * rd1.x, 0.f), fmaxf(rs1.y * rd1.y, 0.f));
            u0.w = pk2(fmaxf(rs1.z * rd1.z, 0.f), fmaxf(rs1.w * rd1.w, 0.f));
            u1.x = pk2(fmaxf(rs2.x * rd2.x, 0.f), fmaxf(rs2.y * rd2.y, 0.f));
            u1.y = pk2(fmaxf(rs2.z * rd2.z, 0.f), fmaxf(rs2.w * rd2.w, 0.f));
            u1.z = pk2(fmaxf(rs3.x * rd3.x, 0.f), fmaxf(rs3.y * rd3.y, 0.f));
            u1.w = pk2(fmaxf(rs3.z * rd3.z, 0.f), fmaxf(rs3.w * rd3.w, 0.f));
        }
    } else { u0.x = u0.y = u0.z = u0.w = 0u; u1 = u0; }
}

template<int BF>
__global__ __launch_bounds__(512, 4)
void fused_kernel(const float* __restrict__ x, const unsigned short* __restrict__ xb,
                  const float* __restrict__ attr,
                  const float* __restrict__ xm, const float* __restrict__ xs,
                  const float* __restrict__ W1, const float* __restrict__ b1,
                  const float* __restrict__ W2, const float* __restrict__ b2,
                  const float* __restrict__ We1, const float* __restrict__ be1,
                  const float* __restrict__ We2, const float* __restrict__ be2,
                  const int* __restrict__ ei, const int* __restrict__ ein,
                  const int* __restrict__ eib, const int* __restrict__ einb,
                  const int* __restrict__ batch,
                  float* __restrict__ ws, int E, int N, int ntiles)
{
    __shared__ float smem[SMEM_F];
    unsigned short* As16 = (unsigned short*)smem;
    unsigned short* Hb   = (unsigned short*)(smem + 4096);
    float* P    = smem + 8448;
    float* b2s  = smem + 8960;
    float* be2s = smem + 8968;

    float* posSum = ws;
    float* negSum = ws + NG;
    float* klSum  = ws + 2 * NG;
    float* tot    = ws + 3 * NG;

    const int bid = (int)blockIdx.x;
    const int t   = (int)threadIdx.x;
    const int wv  = t >> 6;
    const int l   = t & 63;
    const int sub = l & 15;
    const int q   = l >> 4;

    // ---- unified per-wave B set: wave w owns cols w*16..w*16+16 of W1 and We1
    bf16x8 W1f[4], Ehi[4], Elo[4], W2f[4];

#pragma unroll
    for (int pass = 0; pass < 12; pass++) {
        const float* Wsrc = (pass < 4) ? W1 : We1;
        const int p  = (pass >= 8);
        const int kt = pass & 3;
        __syncthreads();
        {
            const int ct = t >> 6, ln = t & 63;
            const int n  = ct * 16 + (ln & 15);
            const int kb = kt * 32 + (ln >> 4) * 8;
            float f[8];
#pragma unroll
            for (int j = 0; j < 8; j++) {
                float v = Wsrc[(kb + j) * D + n];
                f[j] = p ? (v - (float)(__bf16)v) : v;
            }
            uint4 u;
            u.x = pk2(f[0], f[1]); u.y = pk2(f[2], f[3]);
            u.z = pk2(f[4], f[5]); u.w = pk2(f[6], f[7]);
            *(uint4*)(As16 + (ct * 64 + ln) * 8) = u;
        }
        __syncthreads();
        bf16x8 f0 = *(const bf16x8*)(As16 + (wv * 64 + l) * 8);
        if (pass < 4)      W1f[kt] = f0;
        else if (pass < 8) Ehi[kt] = f0;
        else               Elo[kt] = f0;
    }
    // W2 fragments (used only by wv<4 in layer-2)
#pragma unroll
    for (int kt = 0; kt < 4; kt++) {
        const int kb = kt * 32 + q * 8;
        unsigned v[4];
#pragma unroll
        for (int jj = 0; jj < 4; jj++) {
            v[jj] = (sub < 7)
                ? pk2(W2[(kb + 2 * jj) * 7 + sub], W2[(kb + 2 * jj + 1) * 7 + sub])
                : 0u;
        }
        union { uint4 u; bf16x8 b; } cv;
        cv.u.x = v[0]; cv.u.y = v[1]; cv.u.z = v[2]; cv.u.w = v[3];
        W2f[kt] = cv.b;
    }
    // per-lane scalar weights for this wave's 16-col slice
    const float b1w  = b1[wv * 16 + sub];
    const float be1w = be1[wv * 16 + sub];
    const float We2w = We2[wv * 16 + sub];
    if (t < 7) b2s[t] = b2[t];
    if (t == 7) be2s[0] = be2[0];
    __syncthreads();

    // swizzled reader offsets (per kt, lane-constant)
    int roff[4];
#pragma unroll
    for (int kt = 0; kt < 4; kt++) {
        const int g2 = kt + ((q >> 1) << 2);
        roff[kt] = (q * 16 + ((sub & 8) | ((sub ^ g2) & 7))) * 8;
    }
    // swizzled writer slot (lane-constant)
    const int e_  = t >> 3, ks_ = t & 7;
    const int gw  = (ks_ >> 1) | ((ks_ & 1) << 2);
    const int wsl = ((e_ >> 4) * 4 + (ks_ >> 1)) * 64
                  + ((ks_ & 1) * 2) * 16 + ((e_ & 8) | ((e_ ^ gw) & 7));
    unsigned short* wp = As16 + wsl * 8;
    const int k0_ = ks_ * 16;
    const int scA = (sub < 7) ? sub : 6;   // clamped attr column

    // =====================================================================
    // POS sub-loop
    // =====================================================================
    {
        float lpAcc = 0.f;
        int tile = bid;
        float4 rs0, rs1, rs2, rs3, rd0, rd1, rd2, rd3;
        bf16x8 bs0, bs1, bd0, bd1;
        int sN, dN;
        {
            const int Ei0 = tile * 64 + e_;
            const int ix  = Ei0 < E ? Ei0 : E - 1;
            const int s0 = ei[ix], d0 = ei[E + ix];
            if (BF) {
                const bf16x8* ps = (const bf16x8*)(xb + (size_t)s0 * D + k0_);
                const bf16x8* pd = (const bf16x8*)(xb + (size_t)d0 * D + k0_);
                bs0 = ps[0]; bs1 = ps[1]; bd0 = pd[0]; bd1 = pd[1];
            } else {
                const float4* ps = (const float4*)(x + (size_t)s0 * D + k0_);
                const float4* pd = (const float4*)(x + (size_t)d0 * D + k0_);
                rs0 = ps[0]; rs1 = ps[1]; rs2 = ps[2]; rs3 = ps[3];
                rd0 = pd[0]; rd1 = pd[1]; rd2 = pd[2]; rd3 = pd[3];
            }
            const int t1  = tile + NB;
            int Ei1 = (t1 < ntiles) ? t1 * 64 + e_ : 0;
            Ei1 = Ei1 < E ? Ei1 : E - 1;
            sN = ei[Ei1]; dN = ei[E + Ei1];
        }

        for (; tile < ntiles; tile += NB) {
            const int base = tile * 64;
            uint4 u0, u1;
            pack_tile<BF>(base + e_ < E, bs0, bs1, bd0, bd1,
                          rs0, rs1, rs2, rs3, rd0, rd1, rd2, rd3, u0, u1);
            *(uint4*)wp = u0;
            *(uint4*)(wp + 128) = u1;
            const int t1 = tile + NB;
            if (t1 < ntiles) {
                if (BF) {
                    const bf16x8* ps = (const bf16x8*)(xb + (size_t)sN * D + k0_);
                    const bf16x8* pd = (const bf16x8*)(xb + (size_t)dN * D + k0_);
                    bs0 = ps[0]; bs1 = ps[1]; bd0 = pd[0]; bd1 = pd[1];
                } else {
                    const float4* ps = (const float4*)(x + (size_t)sN * D + k0_);
                    const float4* pd = (const float4*)(x + (size_t)dN * D + k0_);
                    rs0 = ps[0]; rs1 = ps[1]; rs2 = ps[2]; rs3 = ps[3];
                    rd0 = pd[0]; rd1 = pd[1]; rd2 = pd[2]; rd3 = pd[3];
                }
                const int t2 = t1 + NB;
                if (t2 < ntiles) {
                    int Ei2 = t2 * 64 + e_;
                    Ei2 = Ei2 < E ? Ei2 : E - 1;
                    sN = ei[Ei2]; dN = ei[E + Ei2];
                }
            }
            // hoisted loss operands
            float atr[4]; int gW;
            if (wv < 4) {
#pragma unroll
                for (int r = 0; r < 4; r++) {
                    int EiE = base + wv * 16 + q * 4 + r;
                    EiE = EiE < E ? EiE : E - 1;
                    atr[r] = attr[(size_t)EiE * 9 + scA];
                }
                int EiW = base + wv * 16 + q * 4 + (sub & 3);
                EiW = EiW < E ? EiW : E - 1;
                gW = eib[EiW];
            } else {
                int EiP = base + (wv - 4) * 16 + sub;
                EiP = EiP < E ? EiP : E - 1;
                gW = eib[EiP];
            }
            bar_lds();                      // barrier G
            // ---- layer 1: every wave, both heads, its own 16-col slice
#pragma unroll
            for (int mt = 0; mt < 4; mt++) {
                const int ab = mt * 2048;
                bf16x8 a0 = *(const bf16x8*)(As16 + ab +        roff[0]);
                bf16x8 a1 = *(const bf16x8*)(As16 + ab +  512 + roff[1]);
                bf16x8 a2 = *(const bf16x8*)(As16 + ab + 1024 + roff[2]);
                bf16x8 a3 = *(const bf16x8*)(As16 + ab + 1536 + roff[3]);
                // W1 head -> Hb
                f32x4 c1 = {0.f, 0.f, 0.f, 0.f};
                c1 = MFMA(a0, W1f[0], c1, 0, 0, 0);
                c1 = MFMA(a1, W1f[1], c1, 0, 0, 0);
                c1 = MFMA(a2, W1f[2], c1, 0, 0, 0);
                c1 = MFMA(a3, W1f[3], c1, 0, 0, 0);
#pragma unroll
                for (int r = 0; r < 4; r++)
                    *(__bf16*)(Hb + (mt * 16 + q * 4 + r) * 136 + wv * 16 + sub) =
                        (__bf16)fmaxf(c1[r] + b1w, 0.f);
                // We head -> P partial
                f32x4 c2 = {0.f, 0.f, 0.f, 0.f};
                c2 = MFMA(a0, Ehi[0], c2, 0, 0, 0);
                c2 = MFMA(a1, Ehi[1], c2, 0, 0, 0);
                c2 = MFMA(a2, Ehi[2], c2, 0, 0, 0);
                c2 = MFMA(a3, Ehi[3], c2, 0, 0, 0);
                c2 = MFMA(a0, Elo[0], c2, 0, 0, 0);
                c2 = MFMA(a1, Elo[1], c2, 0, 0, 0);
                c2 = MFMA(a2, Elo[2], c2, 0, 0, 0);
                c2 = MFMA(a3, Elo[3], c2, 0, 0, 0);
                float zp0 = fmaxf(c2[0] + be1w, 0.f) * We2w;
                float zp1 = fmaxf(c2[1] + be1w, 0.f) * We2w;
                float zp2 = fmaxf(c2[2] + be1w, 0.f) * We2w;
                float zp3 = fmaxf(c2[3] + be1w, 0.f) * We2w;
#pragma unroll
                for (int o = 1; o < 16; o <<= 1) {
                    zp0 += __shfl_xor(zp0, o, 64);
                    zp1 += __shfl_xor(zp1, o, 64);
                    zp2 += __shfl_xor(zp2, o, 64);
                    zp3 += __shfl_xor(zp3, o, 64);
                }
                if (sub < 4) {
                    float vv = (sub == 0) ? zp0 : (sub == 1) ? zp1 : (sub == 2) ? zp2 : zp3;
                    P[(wv << 6) + (mt << 4) + (q << 2) + sub] = vv;
                }
            }
            bar_lds();                      // barrier M
            // ---- layer 2
            if (wv < 4) {
                f32x4 cS = {0.f, 0.f, 0.f, 0.f};
#pragma unroll
                for (int jt = 0; jt < 4; jt++) {
                    bf16x8 hf = *(const bf16x8*)(Hb + (wv * 16 + sub) * 136 + jt * 32 + q * 8);
                    cS = MFMA(hf, W2f[jt], cS, 0, 0, 0);
                }
                float bceP[4];
#pragma unroll
                for (int r = 0; r < 4; r++) {
                    const int EiE = base + wv * 16 + q * 4 + r;
                    const bool on = (sub < 7) && (EiE < E);
                    const float z  = cS[r] + b2s[scA];
                    const float ta = atr[r];
                    const float az  = fabsf(z);
                    const float L   = softplus_neg_abs(az);
                    const float spz = fminf(fmaxf(z, 0.f) + L, 100.f);
                    const float spn = fminf(fmaxf(-z, 0.f) + L, 100.f);
                    bceP[r] = on ? (ta * spn + (1.f - ta) * spz) : 0.f;
                }
#pragma unroll
                for (int o = 1; o < 16; o <<= 1)
#pragma unroll
                    for (int r = 0; r < 4; r++)
                        bceP[r] += __shfl_xor(bceP[r], o, 64);
                const float lossSel = (sub == 0) ? bceP[0] : (sub == 1) ? bceP[1]
                                    : (sub == 2) ? bceP[2] : bceP[3];
                const int EiW = base + wv * 16 + q * 4 + (sub & 3);
                const bool act = (sub < 4) && (EiW < E);
                seg_atomic(posSum, gW, lossSel, act);
            } else {
                const int e2 = (wv - 4) * 16 + sub;
                const int EiP = base + e2;
                const bool vP = (EiP < E) && (q == 0);
                const float zp = P[e2] + P[64 + e2] + P[128 + e2] + P[192 + e2]
                               + P[256 + e2] + P[320 + e2] + P[384 + e2] + P[448 + e2]
                               + be2s[0];
                const float az = fabsf(zp);
                const float L  = softplus_neg_abs(az);
                const float lossP = vP ? fminf(fmaxf(-zp, 0.f) + L, 100.f) : 0.f;
                seg_atomic(posSum, gW, lossP, vP);
                lpAcc += lossP;
            }
        }
        if (wv >= 4) wave_add(tot + 1, lpAcc);
    }

    // =====================================================================
    // NEG sub-loop (We-head only; wave-symmetric)
    // =====================================================================
    {
        float lnAcc = 0.f;
        int tile = bid;
        float4 rs0, rs1, rs2, rs3, rd0, rd1, rd2, rd3;
        bf16x8 bs0, bs1, bd0, bd1;
        int sN, dN;
        {
            const int Ei0 = tile * 64 + e_;
            const int ix  = Ei0 < E ? Ei0 : E - 1;
            const int s0 = ein[ix], d0 = ein[E + ix];
            if (BF) {
                const bf16x8* ps = (const bf16x8*)(xb + (size_t)s0 * D + k0_);
                const bf16x8* pd = (const bf16x8*)(xb + (size_t)d0 * D + k0_);
                bs0 = ps[0]; bs1 = ps[1]; bd0 = pd[0]; bd1 = pd[1];
            } else {
                const float4* ps = (const float4*)(x + (size_t)s0 * D + k0_);
                const float4* pd = (const float4*)(x + (size_t)d0 * D + k0_);
                rs0 = ps[0]; rs1 = ps[1]; rs2 = ps[2]; rs3 = ps[3];
                rd0 = pd[0]; rd1 = pd[1]; rd2 = pd[2]; rd3 = pd[3];
            }
            const int t1  = tile + NB;
            int Ei1 = (t1 < ntiles) ? t1 * 64 + e_ : 0;
            Ei1 = Ei1 < E ? Ei1 : E - 1;
            sN = ein[Ei1]; dN = ein[E + Ei1];
        }

        for (; tile < ntiles; tile += NB) {
            const int base = tile * 64;
            uint4 u0, u1;
            pack_tile<BF>(base + e_ < E, bs0, bs1, bd0, bd1,
                          rs0, rs1, rs2, rs3, rd0, rd1, rd2, rd3, u0, u1);
            *(uint4*)wp = u0;
            *(uint4*)(wp + 128) = u1;
            const int t1 = tile + NB;
            if (t1 < ntiles) {
                if (BF) {
                    const bf16x8* ps = (const bf16x8*)(xb + (size_t)sN * D + k0_);
                    const bf16x8* pd = (const bf16x8*)(xb + (size_t)dN * D + k0_);
                    bs0 = ps[0]; bs1 = ps[1]; bd0 = pd[0]; bd1 = pd[1];
                } else {
                    const float4* ps = (const float4*)(x + (size_t)sN * D + k0_);
                    const float4* pd = (const float4*)(x + (size_t)dN * D + k0_);
                    rs0 = ps[0]; rs1 = ps[1]; rs2 = ps[2]; rs3 = ps[3];
                    rd0 = pd[0]; rd1 = pd[1]; rd2 = pd[2]; rd3 = pd[3];
                }
                const int t2 = t1 + NB;
                if (t2 < ntiles) {
                    int Ei2 = t2 * 64 + e_;
                    Ei2 = Ei2 < E ? Ei2 : E - 1;
                    sN = ein[Ei2]; dN = ein[E + Ei2];
                }
            }
            int gN = 0;
            if (wv == 0) {
                int EiL = base + l;
                EiL = EiL < E ? EiL : E - 1;
                gN = einb[EiL];
            }
            bar_lds();
#pragma unroll
            for (int mt = 0; mt < 4; mt++) {
                const int ab = mt * 2048;
                bf16x8 a0 = *(const bf16x8*)(As16 + ab +        roff[0]);
                bf16x8 a1 = *(const bf16x8*)(As16 + ab +  512 + roff[1]);
                bf16x8 a2 = *(const bf16x8*)(As16 + ab + 1024 + roff[2]);
                bf16x8 a3 = *(const bf16x8*)(As16 + ab + 1536 + roff[3]);
                f32x4 c2 = {0.f, 0.f, 0.f, 0.f};
                c2 = MFMA(a0, Ehi[0], c2, 0, 0, 0);
                c2 = MFMA(a1, Ehi[1], c2, 0, 0, 0);
                c2 = MFMA(a2, Ehi[2], c2, 0, 0, 0);
                c2 = MFMA(a3, Ehi[3], c2, 0, 0, 0);
                c2 = MFMA(a0, Elo[0], c2, 0, 0, 0);
                c2 = MFMA(a1, Elo[1], c2, 0, 0, 0);
                c2 = MFMA(a2, Elo[2], c2, 0, 0, 0);
                c2 = MFMA(a3, Elo[3], c2, 0, 0, 0);
                float zp0 = fmaxf(c2[0] + be1w, 0.f) * We2w;
                float zp1 = fmaxf(c2[1] + be1w, 0.f) * We2w;
                float zp2 = fmaxf(c2[2] + be1w, 0.f) * We2w;
                float zp3 = fmaxf(c2[3] + be1w, 0.f) * We2w;
#pragma unroll
                for (int o = 1; o < 16; o <<= 1) {
                    zp0 += __shfl_xor(zp0, o, 64);
                    zp1 += __shfl_xor(zp1, o, 64);
                    zp2 += __shfl_xor(zp2, o, 64);
                    zp3 += __shfl_xor(zp3, o, 64);
                }
                if (sub < 4) {
                    float vv = (sub == 0) ? zp0 : (sub == 1) ? zp1 : (sub == 2) ? zp2 : zp3;
                    P[(wv << 6) + (mt << 4) + (q << 2) + sub] = vv;
                }
            }
            bar_lds();
            if (wv == 0) {
                const bool valid = (base + l < E);
                float zp = be2s[0];
#pragma unroll
                for (int i = 0; i < 8; i++) zp += P[i * 64 + l];
                float lossN = 0.f;
                if (valid) {
                    const float az = fabsf(zp);
                    const float L  = softplus_neg_abs(az);
                    lossN = fminf(fmaxf(zp, 0.f) + L, 100.f);
                }
                seg_atomic(negSum, gN, lossN, valid);
                lnAcc += valid ? lossN : 0.f;
            }
        }
        if (wv == 0) wave_add(tot + 2, lnAcc);
    }

    // =====================================================================
    // KL sub-loop (no barriers)
    // =====================================================================
    {
        const int hf = l >> 5, li = l & 31;      // 2 rows / wave
        const int gwv = bid * 8 + wv;
        for (int rb = gwv * 2; rb < N; rb += NB * 16) {
            const int row = rb + hf;
            const bool v = (row < N);
            const int rr = v ? row : (N - 1);
            const float4 mm = *(const float4*)(xm + (size_t)rr * D + li * 4);
            const float4 ss = *(const float4*)(xs + (size_t)rr * D + li * 4);
            float a;
            a  = 1.f + 2.f * fmaxf(__logf(ss.x), -1e4f) - mm.x * mm.x - ss.x * ss.x;
            a += 1.f + 2.f * fmaxf(__logf(ss.y), -1e4f) - mm.y * mm.y - ss.y * ss.y;
            a += 1.f + 2.f * fmaxf(__logf(ss.z), -1e4f) - mm.z * mm.z - ss.z * ss.z;
            a += 1.f + 2.f * fmaxf(__logf(ss.w), -1e4f) - mm.w * mm.w - ss.w * ss.w;
#pragma unroll
            for (int o = 1; o < 32; o <<= 1) a += __shfl_xor(a, o, 64);
            if (li == 0 && v) {
                const int g = batch[row];
                atomicAdd(klSum + g, -0.5f * a);
            }
        }
    }
}

__global__ __launch_bounds__(256)
void conv_kernel(const float* __restrict__ x, unsigned short* __restrict__ xb, int n8) {
    const int i0 = (int)(blockIdx.x * 256 + threadIdx.x);
    const int stride = (int)(gridDim.x * 256);
    for (int j = i0; j < n8; j += stride) {
        const float4 a = ((const float4*)x)[(size_t)j * 2];
        const float4 b = ((const float4*)x)[(size_t)j * 2 + 1];
        uint4 u;
        u.x = pk2(a.x, a.y); u.y = pk2(a.z, a.w);
        u.z = pk2(b.x, b.y); u.w = pk2(b.z, b.w);
        ((uint4*)xb)[j] = u;
    }
}

__global__ __launch_bounds__(256)
void final_kernel(const int* __restrict__ eib, const int* __restrict__ einb,
                  const int* __restrict__ nbatch,
                  float* __restrict__ ws, int E, int N, int G) {
    const int g = (int)(blockIdx.x * blockDim.x + threadIdx.x);
    float lg = 0.f;
    if (g < G) {
        const int cP = lbound(eib, E, g + 1) - lbound(eib, E, g);
        const int cN = lbound(einb, E, g + 1) - lbound(einb, E, g);
        const int cB = lbound(nbatch, N, g + 1) - lbound(nbatch, N, g);
        const float fp = fmaxf((float)cP, 1.f);
        const float fn = fmaxf((float)cN, 1.f);
        const float fb = fmaxf((float)cB, 1.f);
        lg = ws[g] / fp + ws[NG + g] / fn + ws[2 * NG + g] / (fb * fb);
    }
#pragma unroll
    for (int o = 1; o < 64; o <<= 1) lg += __shfl_xor(lg, o, 64);
    if ((threadIdx.x & 63u) == 0) atomicAdd(ws + 3 * NG, lg);
}

__global__ void out_kernel(const float* __restrict__ ws, float* __restrict__ out,
                           int E, int G) {
    if (threadIdx.x == 0 && blockIdx.x == 0) {
        out[0] = ws[3 * NG] / (float)G;
        out[1] = 0.5f * (ws[3 * NG + 1] / (float)E + ws[3 * NG + 2] / (float)E);
    }
}

extern "C" void kernel_launch(void* const* d_in, const int* in_sizes, int n_in,
                              void* d_out, int out_size, void* d_ws, size_t ws_size,
                              hipStream_t stream) {
    const float* x    = (const float*)d_in[0];
    const float* attr = (const float*)d_in[1];
    const float* xm   = (const float*)d_in[2];
    const float* xsd  = (const float*)d_in[3];
    const float* W1   = (const float*)d_in[4];
    const float* b1   = (const float*)d_in[5];
    const float* W2   = (const float*)d_in[6];
    const float* b2   = (const float*)d_in[7];
    const float* We1  = (const float*)d_in[8];
    const float* be1  = (const float*)d_in[9];
    const float* We2  = (const float*)d_in[10];
    const float* be2  = (const float*)d_in[11];
    const int* ei     = (const int*)d_in[12];
    const int* ein    = (const int*)d_in[13];
    const int* eib    = (const int*)d_in[14];
    const int* einb   = (const int*)d_in[15];
    const int* batch  = (const int*)d_in[16];

    const int N = in_sizes[0] / D;       // 100000
    const int E = in_sizes[14];          // 600000
    const int G = 1024;

    float* ws = (float*)d_ws;
    unsigned short* xb = (unsigned short*)(ws + 3 * NG + 8);   // 16B-aligned
    const size_t need = (size_t)(3 * NG + 8) * sizeof(float)
                      + (size_t)N * D * sizeof(unsigned short);

    hipMemsetAsync(d_ws, 0, (size_t)(3 * NG + 4) * sizeof(float), stream);

    const int ntiles = (E + 63) / 64;
    if (ws_size >= need) {
        conv_kernel<<<2048, 256, 0, stream>>>(x, xb, N * D / 8);
        fused_kernel<1><<<NB, 512, 0, stream>>>(x, xb, attr, xm, xsd,
                                                W1, b1, W2, b2, We1, be1, We2, be2,
                                                ei, ein, eib, einb, batch,
                                                ws, E, N, ntiles);
    } else {
        fused_kernel<0><<<NB, 512, 0, stream>>>(x, xb, attr, xm, xsd,
                                                W1, b1, W2, b2, We1, be1, We2, be2,
                                                ei, ein, eib, einb, batch,
                                                ws, E, N, ntiles);
    }
    final_kernel<<<(G + 255) / 256, 256, 0, stream>>>(eib, einb, batch,
                                                      ws, E, N, G);
    out_kernel<<<1, 64, 0, stream>>>(ws, (float*)d_out, E, G);
}